// Round 4
// baseline (1972.020 us; speedup 1.0000x reference)
//
#include <hip/hip_runtime.h>

// ---------------------------------------------------------------------------
// FastSpeech-style encoder, round 13:
//  - conv1 GEMM rebuilt around the im2col identity A[m][k+256] = A[m+1][k]:
//    the whole A panel for a 256-row tile is only 264 Hpad rows = 132 KB ->
//    resident in LDS, loaded ONCE (staging was 97% redundant; r1-r3 were
//    LDS-port bound: 192KB reads + 64KB writes per ktile vs 2483cy MFMA).
//    B is read directly global->register in MFMA fragment layout (rows are
//    K-contiguous), 2-deep software pipeline, ZERO barriers in the K-loop.
//  - XCD swizzle kept (gated to the full-size grid; fallback uses identity).
//  - qkv GEMM writes V pre-transposed; attention glds16-staged (unchanged).
// B=32 T=1024 D=256 NH=2 dk=128 D_HID=1024 L=4, conv1 k9p4, conv2 k1.
// ---------------------------------------------------------------------------

#define B_ 32
#define T_ 1024
#define D_ 256
#define NH_ 2
#define DK_ 128
#define DH_ 1024
#define L_ 4
#define MROWS (B_ * T_)        // 32768
#define KCONV (D_ * 9)         // 2304
#define TPAD 1032              // 4 zero + 1024 + 4 zero rows per batch (Hpad)
#define NKT_C1 36              // conv1 K-tiles of 64

typedef unsigned short u16;
typedef short bf16x8 __attribute__((ext_vector_type(8)));
typedef float f32x4 __attribute__((ext_vector_type(4)));
typedef u16 u16x8 __attribute__((ext_vector_type(8)));

__device__ __forceinline__ float bf2f(u16 h) {
    union { unsigned int u; float f; } a;
    a.u = ((unsigned int)h) << 16;
    return a.f;
}

__device__ __forceinline__ u16 f2bf(float f) {
    union { float f; unsigned int u; } a;
    a.f = f;
    unsigned int r = a.u + 0x7fffu + ((a.u >> 16) & 1u);  // RNE
    return (u16)(r >> 16);
}

__device__ __forceinline__ void glds16(const u16* g, u16* l) {
    __builtin_amdgcn_global_load_lds(
        (const __attribute__((address_space(1))) void*)g,
        (__attribute__((address_space(3))) void*)l, 16, 0, 0);
}

// --------------------------- dtype detection -------------------------------
__global__ void detect_kernel(const void* wemb_raw, int* flag) {
    __shared__ int cnt;
    if (threadIdx.x == 0) cnt = 0;
    __syncthreads();
    const u16* p = (const u16*)wemb_raw;
    if (p[256 + threadIdx.x] != 0) atomicAdd(&cnt, 1);
    __syncthreads();
    if (threadIdx.x == 0) *flag = (cnt >= 128) ? 1 : 0;   // 1 = bf16, 0 = fp32
}

__global__ void cvt_any_kernel(const void* __restrict__ src, u16* __restrict__ dst,
                               int n, const int* __restrict__ flag) {
    int i = blockIdx.x * 256 + threadIdx.x;
    if (i >= n) return;
    if (*flag) dst[i] = ((const u16*)src)[i];
    else       dst[i] = f2bf(((const float*)src)[i]);
}

// conv1 weights [l][oc][ic=256][kpos=9] -> [l][oc][kpos*256+ic] bf16
__global__ void w1_reorder2_kernel(const float* __restrict__ srcf,
                                   const u16* __restrict__ srch,
                                   u16* __restrict__ out, int n,
                                   const int* __restrict__ flag) {
    int idx = blockIdx.x * 256 + threadIdx.x;
    if (idx >= n) return;
    int l  = idx / (DH_ * KCONV);
    int r  = idx % (DH_ * KCONV);
    int oc = r / KCONV;
    int kk = r % KCONV;
    int kpos = kk >> 8;
    int ic   = kk & 255;
    size_t si = (size_t)l * DH_ * D_ * 9 + (oc * D_ + ic) * 9 + kpos;
    out[idx] = (*flag) ? srch[si] : f2bf(srcf[si]);
}

__global__ void sentinel_kernel(void* out, int out_size) {
    int i = blockIdx.x * 256 + threadIdx.x;
    if (i < out_size) ((u16*)out)[i] = 0x42F6;  // 123.0 bf16 — "ws too small"
}

// --------------------------- small utility kernels -------------------------

__global__ void embed_kernel(const int* __restrict__ seq, const int* __restrict__ pos,
                             const u16* __restrict__ wemb, const u16* __restrict__ pemb,
                             float* __restrict__ X, float* __restrict__ NP) {
    int row = blockIdx.x;
    int d   = threadIdx.x;
    int s = seq[row];
    int p = pos[row];
    X[(size_t)row * D_ + d] = bf2f(wemb[s * D_ + d]) + bf2f(pemb[p * D_ + d]);
    if (d == 0) NP[row] = (s != 0) ? 1.0f : 0.0f;
}

__global__ void zero_pad_kernel(u16* __restrict__ Hp, int nb) {
    int i = blockIdx.x * 256 + threadIdx.x;
    if (i >= nb * 8 * 256) return;
    int b = i / (8 * 256);
    int r = (i / 256) & 7;
    int d = i & 255;
    int row = (r < 4) ? r : (1024 + r);
    Hp[(size_t)(b * TPAD + row) * D_ + d] = 0;
}

// LN: 4 rows/block (1 wave/row); out -> Hpad layout.
__global__ __launch_bounds__(256)
void ln_kernel(const float* __restrict__ x, const u16* __restrict__ g,
               const u16* __restrict__ bta, u16* __restrict__ outp) {
    int wave = threadIdx.x >> 6, lane = threadIdx.x & 63;
    int row = blockIdx.x * 4 + wave;
    const float* xr = x + (size_t)row * D_;
    float4 v = *(const float4*)&xr[lane * 4];
    float s  = v.x + v.y + v.z + v.w;
    float s2 = v.x * v.x + v.y * v.y + v.z * v.z + v.w * v.w;
#pragma unroll
    for (int d = 1; d < 64; d <<= 1) {
        s  += __shfl_xor(s,  d, 64);
        s2 += __shfl_xor(s2, d, 64);
    }
    float m   = s * (1.0f / 256.0f);
    float var = s2 * (1.0f / 256.0f) - m * m;
    float rr  = rsqrtf(var + 1e-5f);
    size_t orow = (size_t)((row >> 10) * TPAD + 4 + (row & 1023)) * D_;
    float vv[4] = {v.x, v.y, v.z, v.w};
#pragma unroll
    for (int k = 0; k < 4; k++) {
        int d = lane * 4 + k;
        outp[orow + d] = f2bf((vv[k] - m) * rr * bf2f(g[d]) + bf2f(bta[d]));
    }
}

__global__ void out_kernel(const float* __restrict__ X, const float* __restrict__ NP,
                           void* __restrict__ out, int out_size,
                           const int* __restrict__ flag) {
    int i = blockIdx.x * 256 + threadIdx.x;
    if (i >= out_size) return;
    const int n1 = MROWS * D_;
    float v = (i < n1) ? X[i] : NP[i - n1];
    if (*flag) ((u16*)out)[i] = f2bf(v);
    else       ((float*)out)[i] = v;
}

// ------------------------------- MFMA GEMM ---------------------------------
// C[M,N] = A[M,K] @ W^T, W: [N][K] bf16 row-major. 128x128 tile, BK=64.
// AMAP: 0 plain A[M][K]; 1 Hpad rows (K=256); 2 Hpad im2col (K=2304).
// EPI:  0 bf16 (+bias); 1 bf16 (+bias, relu); 2 fp32 (+bias, +resid, *mask);
//       3 qkv: n<512 -> bf16 C stride 512; n>=512 -> V transposed into
//       vout[hb][d][t] (hb = (d>>7) + 2*b).
template <int AMAP, int EPI, int K>
__global__ __launch_bounds__(256)
void gemm_mfma(const u16* __restrict__ A, const u16* __restrict__ W,
               const u16* __restrict__ bias, const float* __restrict__ resid,
               const float* __restrict__ mask, void* __restrict__ Cp,
               u16* __restrict__ vout, int M, int N) {
    __shared__ __align__(16) u16 As[128 * 64];
    __shared__ __align__(16) u16 Bs[128 * 64];
    const int tid  = threadIdx.x;
    const int wave = tid >> 6, lane = tid & 63;
    const int quad = lane >> 4, l15 = lane & 15;
    const int m0 = blockIdx.y * 128, n0 = blockIdx.x * 128;
    const int wm = (wave >> 1) * 64, wn = (wave & 1) * 64;
    const int srow = wave * 32;                  // 32 staged rows per wave
    const int row8 = lane >> 3;                  // 0..7 within 8-row group
    const int grp  = ((lane & 7) ^ row8) * 8;    // swizzled col offset (u16)
    f32x4 acc[4][4] = {};

    const u16* pa;
    {
        int m = m0 + srow + row8;
        if (AMAP == 0) pa = A + (size_t)m * K + grp;
        else {
            int hr = (m >> 10) * TPAD + (m & 1023) + (AMAP == 1 ? 4 : 0);
            pa = A + (size_t)hr * D_ + grp;
        }
    }
    const u16* pb = W + (size_t)(n0 + srow + row8) * K + grp;
    constexpr size_t rsA = (AMAP == 0) ? (size_t)K : (size_t)D_;
    constexpr size_t rsB = (size_t)K;

    u16* lda = &As[srow * 64];
    u16* ldb = &Bs[srow * 64];
    const int rg = (quad ^ (l15 & 7)) * 8;       // read col group (u16 offset)

    int kpos = 0;
    constexpr int nkt = K / 64;
    for (int t = 0; t < nkt; t++) {
#pragma unroll
        for (int q = 0; q < 4; q++) {
            glds16(pa + (size_t)q * 8 * rsA, lda + q * 8 * 64);
            glds16(pb + (size_t)q * 8 * rsB, ldb + q * 8 * 64);
        }
        if (AMAP == 2) {
            if (kpos == 8) { kpos = 0; pa += 64 - 8 * 256; pb += 64 - 8 * 256; }
            else           { kpos++;  pa += 256;           pb += 256; }
        } else { pa += 64; pb += 64; }
        __builtin_amdgcn_s_waitcnt(0);
        __syncthreads();
#pragma unroll
        for (int ks = 0; ks < 2; ks++) {
            bf16x8 af[4], bfr[4];
#pragma unroll
            for (int i = 0; i < 4; i++)
                af[i] = *(const bf16x8*)&As[(wm + i * 16 + l15) * 64 + (rg ^ (ks * 32))];
#pragma unroll
            for (int j = 0; j < 4; j++)
                bfr[j] = *(const bf16x8*)&Bs[(wn + j * 16 + l15) * 64 + (rg ^ (ks * 32))];
#pragma unroll
            for (int i = 0; i < 4; i++)
#pragma unroll
                for (int j = 0; j < 4; j++)
                    acc[i][j] = __builtin_amdgcn_mfma_f32_16x16x32_bf16(
                        af[i], bfr[j], acc[i][j], 0, 0, 0);
        }
        __syncthreads();
    }

    float bv[4];
#pragma unroll
    for (int j = 0; j < 4; j++) bv[j] = bf2f(bias[n0 + wn + j * 16 + l15]);
#pragma unroll
    for (int i = 0; i < 4; i++) {
#pragma unroll
        for (int j = 0; j < 4; j++) {
            int n = n0 + wn + j * 16 + l15;
            int mbase = m0 + wm + i * 16 + quad * 4;
            float o[4];
#pragma unroll
            for (int r = 0; r < 4; r++) {
                float v = acc[i][j][r] + bv[j];
                if (EPI == 1) v = fmaxf(v, 0.0f);
                o[r] = v;
            }
            if (EPI == 2) {
#pragma unroll
                for (int r = 0; r < 4; r++) {
                    int m = mbase + r;
                    float v = (o[r] + resid[(size_t)m * N + n]) * mask[m];
                    ((float*)Cp)[(size_t)m * N + n] = v;
                }
            } else if (EPI == 3) {
                if (n0 < 512) {
#pragma unroll
                    for (int r = 0; r < 4; r++)
                        ((u16*)Cp)[(size_t)(mbase + r) * 512 + n] = f2bf(o[r]);
                } else {
                    int dg = n - 512;                    // 0..255
                    int bb = mbase >> 10, tt = mbase & 1023;
                    ushort4 pk;
                    pk.x = f2bf(o[0]); pk.y = f2bf(o[1]);
                    pk.z = f2bf(o[2]); pk.w = f2bf(o[3]);
                    *(ushort4*)&vout[(size_t)((dg >> 7) + (bb << 1)) * (128 * 1024)
                                     + (size_t)(dg & 127) * 1024 + tt] = pk;
                }
            } else {
#pragma unroll
                for (int r = 0; r < 4; r++)
                    ((u16*)Cp)[(size_t)(mbase + r) * N + n] = f2bf(o[r]);
            }
        }
    }
}

// ----------------- conv1 GEMM: A-resident, B-from-global -------------------
// C[M,1024] = im2col(Hpad)[M,2304] @ W1R^T, bias+relu, bf16 out.
// Key identity: A[m][k] = Hpad[(hr0+m)*256 + k] -> the A panel for a
// 256-row m-tile over ALL of K is just 264 Hpad rows = 132 KB. Load it into
// LDS ONCE (XOR-chunk swizzle per row, same involution as the staged path),
// then the K-loop has NO barriers and NO staging:
//   { 8 global B-frag loads (tile t+1, 2-deep static pipeline) |
//     16 ds_read_b128 A-frags | 64 MFMA }.
// B frags are read straight from W1R in MFMA layout (rows K-contiguous:
// lane reads 16B at [n0+wn+nf*16+l15][t*64+ks*32+quad*8]); B k-slices are
// L1/L2-resident (panel 1.18 MB per XCD). Per ktile: LDS 128KB reads, 0
// writes, vs r1's 192+64 -> LDS no longer co-critical with MFMA (2483 cyc).
// Tile t, k-slice ks reads panel rows [t>>2 .. 255+(t>>2)], chunk
// (t&3)*8 + ks*4 + quad (16B units), XORed with (row&7).
__global__ __launch_bounds__(512, 2)
void gemm_conv1_ar(const u16* __restrict__ Ag, const u16* __restrict__ Wg,
                   const u16* __restrict__ bias, u16* __restrict__ Cp) {
    __shared__ __align__(16) u16 Ap[264 * 256];   // 132 KB
    const int tid  = threadIdx.x;
    const int lane = tid & 63;
    const int wave = tid >> 6;
    const int quad = lane >> 4, l15 = lane & 15;
    const int wr = wave >> 2, wc = wave & 3;
    // XCD-aware swizzle only for the full grid (4 x 128); else identity.
    int ntile, mtile;
    if (gridDim.y == 128) {
        const int f   = blockIdx.y * 4 + blockIdx.x;
        const int xcd = f & 7, pos = f >> 3;       // pos 0..63
        ntile = xcd >> 1;                          // n-column per XCD pair
        mtile = ((xcd & 1) << 6) + pos;            // 0..127
    } else { ntile = blockIdx.x; mtile = blockIdx.y; }
    const int m0 = mtile << 8, n0 = ntile << 8;
    const int hr0 = (m0 >> 10) * TPAD + (m0 & 1023);

    // ---- one-time A panel load: 264 rows x 32 chunks of 16B = 8448 ----
    // LDS[r][cc] = A[r][cc ^ (r&7)]  (source pre-swizzled, dest linear)
#pragma unroll
    for (int k = 0; k < 16; k++) {
        int c = k * 512 + tid;
        int r = c >> 5, cc = c & 31;
        glds16(Ag + (size_t)(hr0 + r) * 256 + ((cc ^ (r & 7)) * 8),
               &Ap[(size_t)(k * 512 + wave * 64) * 8]);
    }
    if (tid < 256) {                               // chunks 8192..8447
        int c = 8192 + tid;
        int r = c >> 5, cc = c & 31;
        glds16(Ag + (size_t)(hr0 + r) * 256 + ((cc ^ (r & 7)) * 8),
               &Ap[(size_t)(8192 + wave * 64) * 8]);
    }

    // ---- B walking pointers (one per n-frag), MFMA fragment layout ----
    const u16* pwB = Wg + (size_t)(n0 + wc * 64 + l15) * KCONV + quad * 8;
    const u16* pn0 = pwB;
    const u16* pn1 = pwB + 1 * 16 * KCONV;
    const u16* pn2 = pwB + 2 * 16 * KCONV;
    const u16* pn3 = pwB + 3 * 16 * KCONV;
    const int arow_l = wr * 128 + l15;
    f32x4 acc[8][4] = {};
    bf16x8 bA[8], bB[8];

#define LOADB(BS) do {                                                        \
    BS[0] = *(const bf16x8*)pn0; BS[1] = *(const bf16x8*)(pn0 + 32); pn0 += 64; \
    BS[2] = *(const bf16x8*)pn1; BS[3] = *(const bf16x8*)(pn1 + 32); pn1 += 64; \
    BS[4] = *(const bf16x8*)pn2; BS[5] = *(const bf16x8*)(pn2 + 32); pn2 += 64; \
    BS[6] = *(const bf16x8*)pn3; BS[7] = *(const bf16x8*)(pn3 + 32); pn3 += 64; \
} while (0)

#define TILE(T, BS) do {                                                      \
    const int _ro  = (T) >> 2;                                                \
    const int _swz = (l15 + _ro) & 7;                                         \
    const int _c0  = ((((T) & 3) * 8 + quad) ^ _swz) * 8;                     \
    const int _bse = (arow_l + _ro) * 256;                                    \
    bf16x8 _a[8];                                                             \
    _Pragma("unroll")                                                         \
    for (int mf = 0; mf < 8; mf++)                                            \
        _a[mf] = *(const bf16x8*)&Ap[_bse + mf * 4096 + _c0];                 \
    __builtin_amdgcn_s_setprio(1);                                            \
    _Pragma("unroll")                                                         \
    for (int mf = 0; mf < 8; mf++) {                                          \
        acc[mf][0] = __builtin_amdgcn_mfma_f32_16x16x32_bf16(_a[mf], BS[0], acc[mf][0], 0, 0, 0); \
        acc[mf][1] = __builtin_amdgcn_mfma_f32_16x16x32_bf16(_a[mf], BS[2], acc[mf][1], 0, 0, 0); \
        acc[mf][2] = __builtin_amdgcn_mfma_f32_16x16x32_bf16(_a[mf], BS[4], acc[mf][2], 0, 0, 0); \
        acc[mf][3] = __builtin_amdgcn_mfma_f32_16x16x32_bf16(_a[mf], BS[6], acc[mf][3], 0, 0, 0); \
    }                                                                         \
    __builtin_amdgcn_s_setprio(0);                                            \
    _Pragma("unroll")                                                         \
    for (int mf = 0; mf < 8; mf++)                                            \
        _a[mf] = *(const bf16x8*)&Ap[_bse + mf * 4096 + (_c0 ^ 32)];          \
    __builtin_amdgcn_s_setprio(1);                                            \
    _Pragma("unroll")                                                         \
    for (int mf = 0; mf < 8; mf++) {                                          \
        acc[mf][0] = __builtin_amdgcn_mfma_f32_16x16x32_bf16(_a[mf], BS[1], acc[mf][0], 0, 0, 0); \
        acc[mf][1] = __builtin_amdgcn_mfma_f32_16x16x32_bf16(_a[mf], BS[3], acc[mf][1], 0, 0, 0); \
        acc[mf][2] = __builtin_amdgcn_mfma_f32_16x16x32_bf16(_a[mf], BS[5], acc[mf][2], 0, 0, 0); \
        acc[mf][3] = __builtin_amdgcn_mfma_f32_16x16x32_bf16(_a[mf], BS[7], acc[mf][3], 0, 0, 0); \
    }                                                                         \
    __builtin_amdgcn_s_setprio(0);                                            \
} while (0)

    LOADB(bA);                       // B(0) into registers (waits auto-count)
    __builtin_amdgcn_s_waitcnt(0);   // A panel staged
    __syncthreads();

#pragma unroll 1
    for (int tt = 0; tt < NKT_C1; tt += 2) {
        LOADB(bB);                   // B(tt+1)
        TILE(tt, bA);
        if (tt + 2 < NKT_C1) LOADB(bA);   // B(tt+2)
        TILE(tt + 1, bB);
    }

#undef LOADB
#undef TILE

    // epilogue: bias + relu -> bf16 C [M][1024]
    float bv[4];
#pragma unroll
    for (int nf = 0; nf < 4; nf++)
        bv[nf] = bf2f(bias[n0 + wc * 64 + nf * 16 + l15]);
#pragma unroll
    for (int mf = 0; mf < 8; mf++) {
        const int mr = m0 + wr * 128 + mf * 16 + quad * 4;
#pragma unroll
        for (int nf = 0; nf < 4; nf++) {
            const int cc = n0 + wc * 64 + nf * 16 + l15;
#pragma unroll
            for (int r = 0; r < 4; r++) {
                float v = fmaxf(acc[mf][nf][r] + bv[nf], 0.0f);
                Cp[(size_t)(mr + r) * 1024 + cc] = f2bf(v);
            }
        }
    }
}

// --------------------------- flash MFMA attention --------------------------
// QKV [Mc][512] bf16 (q|k, head h at cols h*128 / 256+h*128).
// Vg [hb][128 d][1024 t] bf16 (pre-transposed V).
// Grid (hb fastest -> XCD locality, qt8 0..7), 256 thr, 128 q/block
// (2 sub-tiles of 16 q per wave). K-tiles of 64 keys, glds16 staging with
// XOR-chunk swizzle, B-frags shared across subs, online softmax, O -> Hpad.
// LDS 54KB: Ks 64x128, Vt 128x64, Ps 4x32x72, npS.
__global__ __launch_bounds__(256, 2)
void attn_mfma(const u16* __restrict__ QKV, const u16* __restrict__ Vg,
               const float* __restrict__ NPg, u16* __restrict__ Hp) {
    __shared__ __align__(16) u16 Ks[64 * 128];
    __shared__ __align__(16) u16 Vt[128 * 64];
    __shared__ __align__(16) u16 Ps[4 * 32 * 72];
    __shared__ float npS[1024];
    const int tid  = threadIdx.x;
    const int wave = tid >> 6, lane = tid & 63;
    const int quad = lane >> 4, l15 = lane & 15;
    const int hb = blockIdx.x;
    const int h = hb & (NH_ - 1), b = hb >> 1;
    const int t0 = blockIdx.y * 128;
    const float scale = 0.08838834764831845f;  // 1/sqrt(128)
    u16* Psw = Ps + wave * 32 * 72;
    const u16* Vgh = Vg + (size_t)hb * (128 * 1024);

    for (int i = tid; i < 1024; i += 256) npS[i] = NPg[b * 1024 + i];

    bf16x8 q_a[2][4];
#pragma unroll
    for (int sub = 0; sub < 2; sub++)
#pragma unroll
        for (int s = 0; s < 4; s++)
            q_a[sub][s] = *(const bf16x8*)(QKV
                + (size_t)(b * 1024 + t0 + sub * 64 + wave * 16 + l15) * 512
                + h * DK_ + s * 32 + quad * 8);

    float m_st[2][4], l_st[2][4];
    f32x4 oacc[2][8] = {};
#pragma unroll
    for (int sub = 0; sub < 2; sub++)
#pragma unroll
        for (int r = 0; r < 4; r++) { m_st[sub][r] = -1e30f; l_st[sub][r] = 0.0f; }

    for (int kk = 0; kk < 16; kk++) {
        const int k0 = kk * 64;
        if (kk) __syncthreads();   // prev tile's Ks/Vt reads complete
        // ---- stage K tile + V^T tile via glds16 (XOR-chunk swizzle) ----
#pragma unroll
        for (int i = 0; i < 4; i++) {
            int c = i * 256 + tid;
            int key = c >> 4, gk = (c & 15) ^ (key & 15);
            glds16(QKV + (size_t)(b * 1024 + k0 + key) * 512 + 256 + h * DK_ + gk * 8,
                   Ks + (size_t)(i * 256 + wave * 64) * 8);
            int d = c >> 3, gv = (c & 7) ^ (d & 7);
            glds16(Vgh + (size_t)d * 1024 + k0 + gv * 8,
                   Vt + (size_t)(i * 256 + wave * 64) * 8);
        }
        __builtin_amdgcn_s_waitcnt(0);
        __syncthreads();

        // ---- S = Q K^T, kb shared across both q-subs ----
        f32x4 s4[2][4] = {};
#pragma unroll
        for (int nt = 0; nt < 4; nt++) {
#pragma unroll
            for (int s = 0; s < 4; s++) {
                bf16x8 kb = *(const bf16x8*)&Ks[(nt * 16 + l15) * 128
                                                + ((s * 4 + quad) ^ l15) * 8];
                s4[0][nt] = __builtin_amdgcn_mfma_f32_16x16x32_bf16(
                    q_a[0][s], kb, s4[0][nt], 0, 0, 0);
                s4[1][nt] = __builtin_amdgcn_mfma_f32_16x16x32_bf16(
                    q_a[1][s], kb, s4[1][nt], 0, 0, 0);
            }
        }

        // ---- mask + online softmax + P->LDS (per sub; Ps is wave-private) --
#pragma unroll
        for (int sub = 0; sub < 2; sub++) {
#pragma unroll
            for (int nt = 0; nt < 4; nt++) {
                bool pad = (npS[k0 + nt * 16 + l15] == 0.0f);
#pragma unroll
                for (int r = 0; r < 4; r++)
                    s4[sub][nt][r] = pad ? -1e30f : s4[sub][nt][r] * scale;
            }
            float alpha[4];
#pragma unroll
            for (int r = 0; r < 4; r++) {
                float v = fmaxf(fmaxf(s4[sub][0][r], s4[sub][1][r]),
                                fmaxf(s4[sub][2][r], s4[sub][3][r]));
#pragma unroll
                for (int d = 1; d < 16; d <<= 1) v = fmaxf(v, __shfl_xor(v, d, 64));
                float mnew = fmaxf(m_st[sub][r], v);
                alpha[r] = __expf(m_st[sub][r] - mnew);
                m_st[sub][r] = mnew;
                l_st[sub][r] *= alpha[r];
            }
#pragma unroll
            for (int nt = 0; nt < 4; nt++)
#pragma unroll
                for (int r = 0; r < 4; r++)
                    s4[sub][nt][r] = __expf(s4[sub][nt][r] - m_st[sub][r]);
#pragma unroll
            for (int r = 0; r < 4; r++) {
                float v = s4[sub][0][r] + s4[sub][1][r] + s4[sub][2][r] + s4[sub][3][r];
#pragma unroll
                for (int d = 1; d < 16; d <<= 1) v += __shfl_xor(v, d, 64);
                l_st[sub][r] += v;
            }
#pragma unroll
            for (int dt = 0; dt < 8; dt++)
#pragma unroll
                for (int r = 0; r < 4; r++) oacc[sub][dt][r] *= alpha[r];
#pragma unroll
            for (int nt = 0; nt < 4; nt++)
#pragma unroll
                for (int r = 0; r < 4; r++)
                    Psw[(sub * 16 + quad * 4 + r) * 72 + nt * 16 + l15] =
                        f2bf(s4[sub][nt][r]);
        }

        // ---- O += P V, vb shared across both q-subs ----
#pragma unroll
        for (int ks = 0; ks < 2; ks++) {
            bf16x8 pa0 = *(const bf16x8*)&Psw[l15 * 72 + ks * 32 + quad * 8];
            bf16x8 pa1 = *(const bf16x8*)&Psw[(16 + l15) * 72 + ks * 32 + quad * 8];
#pragma unroll
            for (int dt = 0; dt < 8; dt++) {
                int d = dt * 16 + l15;
                bf16x8 vb = *(const bf16x8*)&Vt[d * 64
                                                + (((ks * 4 + quad) ^ (d & 7)) * 8)];
                oacc[0][dt] = __builtin_amdgcn_mfma_f32_16x16x32_bf16(
                    pa0, vb, oacc[0][dt], 0, 0, 0);
                oacc[1][dt] = __builtin_amdgcn_mfma_f32_16x16x32_bf16(
                    pa1, vb, oacc[1][dt], 0, 0, 0);
            }
        }
    }

    // ---- epilogue: O / l -> Hpad ----
#pragma unroll
    for (int sub = 0; sub < 2; sub++)
#pragma unroll
        for (int r = 0; r < 4; r++) {
            float inv = 1.0f / l_st[sub][r];
            int t = t0 + sub * 64 + wave * 16 + quad * 4 + r;
            size_t orow = (size_t)(b * TPAD + 4 + t) * D_ + h * DK_;
#pragma unroll
            for (int dt = 0; dt < 8; dt++)
                Hp[orow + dt * 16 + l15] = f2bf(oacc[sub][dt][r] * inv);
        }
}

// ------------------------------- driver ------------------------------------

static inline int cdiv(int a, int b) { return (a + b - 1) / b; }

extern "C" void kernel_launch(void* const* d_in, const int* in_sizes, int n_in,
                              void* d_out, int out_size, void* d_ws, size_t ws_size,
                              hipStream_t stream) {
    const int* seq = (const int*)d_in[0];
    const int* pos = (const int*)d_in[1];
    (void)in_sizes; (void)n_in;

    int   cb = 8, w1L = 1;
    int*   FLAG; float* X; float* NP; u16* Hpad; u16* SCR; u16* W1R;
    u16 *WEMB, *PEMB, *QKVW, *QKVB, *FCW, *FCB, *G1c, *B1c, *C1B, *C2W, *C2B, *G2c, *B2c;

    unsigned char* wsb = (unsigned char*)d_ws;
    size_t off;
    auto build = [&](int cb_, int w1L_) -> size_t {
        off = 0;
        auto take = [&](size_t bytes) {
            unsigned char* p = wsb + off;
            off += (bytes + 255) & ~(size_t)255;
            return p;
        };
        FLAG = (int*)  take(4);
        X    = (float*)take((size_t)MROWS * D_ * 4);
        NP   = (float*)take((size_t)MROWS * 4);
        Hpad = (u16*)  take((size_t)cb_ * TPAD * D_ * 2);
        SCR  = (u16*)  take((size_t)cb_ * T_ * DH_ * 2);
        W1R  = (u16*)  take((size_t)w1L_ * DH_ * KCONV * 2);
        WEMB = (u16*)  take((size_t)300 * D_ * 2);
        PEMB = (u16*)  take((size_t)3001 * D_ * 2);
        QKVW = (u16*)  take((size_t)L_ * 3 * D_ * D_ * 2);
        QKVB = (u16*)  take((size_t)L_ * 3 * D_ * 2);
        FCW  = (u16*)  take((size_t)L_ * D_ * D_ * 2);
        FCB  = (u16*)  take((size_t)L_ * D_ * 2);
        G1c  = (u16*)  take((size_t)L_ * D_ * 2);
        B1c  = (u16*)  take((size_t)L_ * D_ * 2);
        C1B  = (u16*)  take((size_t)L_ * DH_ * 2);
        C2W  = (u16*)  take((size_t)L_ * D_ * DH_ * 2);
        C2B  = (u16*)  take((size_t)L_ * D_ * 2);
        G2c  = (u16*)  take((size_t)L_ * D_ * 2);
        B2c  = (u16*)  take((size_t)L_ * D_ * 2);
        return off;
    };
    if      (build(32, L_) <= ws_size) { cb = 32; w1L = L_; }
    else if (build(8,  L_) <= ws_size) { cb = 8;  w1L = L_; }
    else if (build(8,  1)  <= ws_size) { cb = 8;  w1L = 1;  }
    else {
        sentinel_kernel<<<cdiv(out_size, 256), 256, 0, stream>>>(d_out, out_size);
        return;
    }
    const int nch = B_ / cb;
    const int Mc  = cb * T_;

    detect_kernel<<<1, 256, 0, stream>>>(d_in[2], FLAG);
    auto cvt = [&](const void* src, u16* dst, int n) {
        cvt_any_kernel<<<cdiv(n, 256), 256, 0, stream>>>(src, dst, n, FLAG);
    };
    cvt(d_in[2],  WEMB, 300 * D_);
    cvt(d_in[3],  PEMB, 3001 * D_);
    cvt(d_in[4],  QKVW, L_ * 3 * D_ * D_);
    cvt(d_in[5],  QKVB, L_ * 3 * D_);
    cvt(d_in[6],  FCW,  L_ * D_ * D_);
    cvt(d_in[7],  FCB,  L_ * D_);
    cvt(d_in[8],  G1c,  L_ * D_);
    cvt(d_in[9],  B1c,  L_ * D_);
    cvt(d_in[11], C1B,  L_ * DH_);
    cvt(d_in[12], C2W,  L_ * D_ * DH_);
    cvt(d_in[13], C2B,  L_ * D_);
    cvt(d_in[14], G2c,  L_ * D_);
    cvt(d_in[15], B2c,  L_ * D_);
    if (w1L == L_) {
        int n = L_ * DH_ * KCONV;
        w1_reorder2_kernel<<<cdiv(n, 256), 256, 0, stream>>>(
            (const float*)d_in[10], (const u16*)d_in[10], W1R, n, FLAG);
    }

    embed_kernel<<<MROWS, 256, 0, stream>>>(seq, pos, WEMB, PEMB, X, NP);
    zero_pad_kernel<<<cb * 8, 256, 0, stream>>>(Hpad, cb);

    for (int l = 0; l < L_; l++) {
        for (int c = 0; c < nch; c++) {
            const size_t ro = (size_t)c * Mc;
            u16* QKV = SCR;                              // [Mc][512] q|k
            u16* Vg  = SCR + (size_t)Mc * 512;           // [NH*cb][128][1024]
            ln_kernel<<<Mc / 4, 256, 0, stream>>>(
                X + ro * D_, G1c + l * D_, B1c + l * D_, Hpad);
            gemm_mfma<1, 3, 256><<<dim3(6, Mc / 128), 256, 0, stream>>>(
                Hpad, QKVW + (size_t)l * 3 * D_ * D_, QKVB + l * 3 * D_,
                nullptr, nullptr, QKV, Vg, Mc, 768);
            attn_mfma<<<dim3(NH_ * cb, 8), 256, 0, stream>>>(
                QKV, Vg, NP + ro, Hpad);
            gemm_mfma<1, 2, 256><<<dim3(2, Mc / 128), 256, 0, stream>>>(
                Hpad, FCW + (size_t)l * D_ * D_, FCB + l * D_,
                X + ro * D_, NP + ro, X + ro * D_, nullptr, Mc, D_);
        }
        const u16* w1p = W1R + (w1L == L_ ? (size_t)l * DH_ * KCONV : 0);
        if (w1L != L_) {
            int n = DH_ * KCONV;
            w1_reorder2_kernel<<<cdiv(n, 256), 256, 0, stream>>>(
                (const float*)d_in[10] + (size_t)l * DH_ * D_ * 9,
                (const u16*)d_in[10] + (size_t)l * DH_ * D_ * 9,
                W1R, n, FLAG);
        }
        for (int c = 0; c < nch; c++) {
            const size_t ro = (size_t)c * Mc;
            ln_kernel<<<Mc / 4, 256, 0, stream>>>(
                X + ro * D_, G2c + l * D_, B2c + l * D_, Hpad);
            gemm_conv1_ar<<<dim3(4, Mc / 256), 512, 0, stream>>>(
                Hpad, w1p, C1B + l * DH_, SCR);
            gemm_mfma<0, 2, 1024><<<dim3(2, Mc / 128), 256, 0, stream>>>(
                SCR, C2W + (size_t)l * D_ * DH_, C2B + l * D_,
                X + ro * D_, NP + ro, X + ro * D_, nullptr, Mc, D_);
        }
    }

    out_kernel<<<cdiv(out_size, 256), 256, 0, stream>>>(X, NP, d_out, out_size, FLAG);
}

// Round 5
// 1396.653 us; speedup vs baseline: 1.4120x; 1.4120x over previous
//
#include <hip/hip_runtime.h>

// ---------------------------------------------------------------------------
// FastSpeech-style encoder, round 14:
//  - conv1 GEMM: exact revert to the round-10/r1 verified structure
//    (256x256 tile, BK=64, 8-wave, 4-phase with reads+MFMA in one region,
//    4 barriers + vmcnt(4)/ktile, 142.5us, 47% MfmaUtil, 0 conflicts)
//    + ONE delta: XCD-aware bijective block swizzle (FETCH 180->145 MB,
//    verified traffic reduction in r2/r3, never tested alone).
//  - r4's A-resident/B-global design is abandoned: it spilled registers
//    (WRITE 606MB scratch) and hit 9.4M LDS bank conflicts at 512B row
//    stride (bank model unverified for that stride).
//  - qkv GEMM writes V pre-transposed; attention glds16-staged (unchanged).
// B=32 T=1024 D=256 NH=2 dk=128 D_HID=1024 L=4, conv1 k9p4, conv2 k1.
// ---------------------------------------------------------------------------

#define B_ 32
#define T_ 1024
#define D_ 256
#define NH_ 2
#define DK_ 128
#define DH_ 1024
#define L_ 4
#define MROWS (B_ * T_)        // 32768
#define KCONV (D_ * 9)         // 2304
#define TPAD 1032              // 4 zero + 1024 + 4 zero rows per batch (Hpad)
#define NKT_C1 36              // conv1 K-tiles of 64

typedef unsigned short u16;
typedef short bf16x8 __attribute__((ext_vector_type(8)));
typedef float f32x4 __attribute__((ext_vector_type(4)));
typedef u16 u16x8 __attribute__((ext_vector_type(8)));

__device__ __forceinline__ float bf2f(u16 h) {
    union { unsigned int u; float f; } a;
    a.u = ((unsigned int)h) << 16;
    return a.f;
}

__device__ __forceinline__ u16 f2bf(float f) {
    union { float f; unsigned int u; } a;
    a.f = f;
    unsigned int r = a.u + 0x7fffu + ((a.u >> 16) & 1u);  // RNE
    return (u16)(r >> 16);
}

__device__ __forceinline__ void glds16(const u16* g, u16* l) {
    __builtin_amdgcn_global_load_lds(
        (const __attribute__((address_space(1))) void*)g,
        (__attribute__((address_space(3))) void*)l, 16, 0, 0);
}

// --------------------------- dtype detection -------------------------------
__global__ void detect_kernel(const void* wemb_raw, int* flag) {
    __shared__ int cnt;
    if (threadIdx.x == 0) cnt = 0;
    __syncthreads();
    const u16* p = (const u16*)wemb_raw;
    if (p[256 + threadIdx.x] != 0) atomicAdd(&cnt, 1);
    __syncthreads();
    if (threadIdx.x == 0) *flag = (cnt >= 128) ? 1 : 0;   // 1 = bf16, 0 = fp32
}

__global__ void cvt_any_kernel(const void* __restrict__ src, u16* __restrict__ dst,
                               int n, const int* __restrict__ flag) {
    int i = blockIdx.x * 256 + threadIdx.x;
    if (i >= n) return;
    if (*flag) dst[i] = ((const u16*)src)[i];
    else       dst[i] = f2bf(((const float*)src)[i]);
}

// conv1 weights [l][oc][ic=256][kpos=9] -> [l][oc][kpos*256+ic] bf16
__global__ void w1_reorder2_kernel(const float* __restrict__ srcf,
                                   const u16* __restrict__ srch,
                                   u16* __restrict__ out, int n,
                                   const int* __restrict__ flag) {
    int idx = blockIdx.x * 256 + threadIdx.x;
    if (idx >= n) return;
    int l  = idx / (DH_ * KCONV);
    int r  = idx % (DH_ * KCONV);
    int oc = r / KCONV;
    int kk = r % KCONV;
    int kpos = kk >> 8;
    int ic   = kk & 255;
    size_t si = (size_t)l * DH_ * D_ * 9 + (oc * D_ + ic) * 9 + kpos;
    out[idx] = (*flag) ? srch[si] : f2bf(srcf[si]);
}

__global__ void sentinel_kernel(void* out, int out_size) {
    int i = blockIdx.x * 256 + threadIdx.x;
    if (i < out_size) ((u16*)out)[i] = 0x42F6;  // 123.0 bf16 — "ws too small"
}

// --------------------------- small utility kernels -------------------------

__global__ void embed_kernel(const int* __restrict__ seq, const int* __restrict__ pos,
                             const u16* __restrict__ wemb, const u16* __restrict__ pemb,
                             float* __restrict__ X, float* __restrict__ NP) {
    int row = blockIdx.x;
    int d   = threadIdx.x;
    int s = seq[row];
    int p = pos[row];
    X[(size_t)row * D_ + d] = bf2f(wemb[s * D_ + d]) + bf2f(pemb[p * D_ + d]);
    if (d == 0) NP[row] = (s != 0) ? 1.0f : 0.0f;
}

__global__ void zero_pad_kernel(u16* __restrict__ Hp, int nb) {
    int i = blockIdx.x * 256 + threadIdx.x;
    if (i >= nb * 8 * 256) return;
    int b = i / (8 * 256);
    int r = (i / 256) & 7;
    int d = i & 255;
    int row = (r < 4) ? r : (1024 + r);
    Hp[(size_t)(b * TPAD + row) * D_ + d] = 0;
}

// LN: 4 rows/block (1 wave/row); out -> Hpad layout.
__global__ __launch_bounds__(256)
void ln_kernel(const float* __restrict__ x, const u16* __restrict__ g,
               const u16* __restrict__ bta, u16* __restrict__ outp) {
    int wave = threadIdx.x >> 6, lane = threadIdx.x & 63;
    int row = blockIdx.x * 4 + wave;
    const float* xr = x + (size_t)row * D_;
    float4 v = *(const float4*)&xr[lane * 4];
    float s  = v.x + v.y + v.z + v.w;
    float s2 = v.x * v.x + v.y * v.y + v.z * v.z + v.w * v.w;
#pragma unroll
    for (int d = 1; d < 64; d <<= 1) {
        s  += __shfl_xor(s,  d, 64);
        s2 += __shfl_xor(s2, d, 64);
    }
    float m   = s * (1.0f / 256.0f);
    float var = s2 * (1.0f / 256.0f) - m * m;
    float rr  = rsqrtf(var + 1e-5f);
    size_t orow = (size_t)((row >> 10) * TPAD + 4 + (row & 1023)) * D_;
    float vv[4] = {v.x, v.y, v.z, v.w};
#pragma unroll
    for (int k = 0; k < 4; k++) {
        int d = lane * 4 + k;
        outp[orow + d] = f2bf((vv[k] - m) * rr * bf2f(g[d]) + bf2f(bta[d]));
    }
}

__global__ void out_kernel(const float* __restrict__ X, const float* __restrict__ NP,
                           void* __restrict__ out, int out_size,
                           const int* __restrict__ flag) {
    int i = blockIdx.x * 256 + threadIdx.x;
    if (i >= out_size) return;
    const int n1 = MROWS * D_;
    float v = (i < n1) ? X[i] : NP[i - n1];
    if (*flag) ((u16*)out)[i] = f2bf(v);
    else       ((float*)out)[i] = v;
}

// ------------------------------- MFMA GEMM ---------------------------------
// C[M,N] = A[M,K] @ W^T, W: [N][K] bf16 row-major. 128x128 tile, BK=64.
// AMAP: 0 plain A[M][K]; 1 Hpad rows (K=256); 2 Hpad im2col (K=2304).
// EPI:  0 bf16 (+bias); 1 bf16 (+bias, relu); 2 fp32 (+bias, +resid, *mask);
//       3 qkv: n<512 -> bf16 C stride 512; n>=512 -> V transposed into
//       vout[hb][d][t] (hb = (d>>7) + 2*b).
template <int AMAP, int EPI, int K>
__global__ __launch_bounds__(256)
void gemm_mfma(const u16* __restrict__ A, const u16* __restrict__ W,
               const u16* __restrict__ bias, const float* __restrict__ resid,
               const float* __restrict__ mask, void* __restrict__ Cp,
               u16* __restrict__ vout, int M, int N) {
    __shared__ __align__(16) u16 As[128 * 64];
    __shared__ __align__(16) u16 Bs[128 * 64];
    const int tid  = threadIdx.x;
    const int wave = tid >> 6, lane = tid & 63;
    const int quad = lane >> 4, l15 = lane & 15;
    const int m0 = blockIdx.y * 128, n0 = blockIdx.x * 128;
    const int wm = (wave >> 1) * 64, wn = (wave & 1) * 64;
    const int srow = wave * 32;                  // 32 staged rows per wave
    const int row8 = lane >> 3;                  // 0..7 within 8-row group
    const int grp  = ((lane & 7) ^ row8) * 8;    // swizzled col offset (u16)
    f32x4 acc[4][4] = {};

    const u16* pa;
    {
        int m = m0 + srow + row8;
        if (AMAP == 0) pa = A + (size_t)m * K + grp;
        else {
            int hr = (m >> 10) * TPAD + (m & 1023) + (AMAP == 1 ? 4 : 0);
            pa = A + (size_t)hr * D_ + grp;
        }
    }
    const u16* pb = W + (size_t)(n0 + srow + row8) * K + grp;
    constexpr size_t rsA = (AMAP == 0) ? (size_t)K : (size_t)D_;
    constexpr size_t rsB = (size_t)K;

    u16* lda = &As[srow * 64];
    u16* ldb = &Bs[srow * 64];
    const int rg = (quad ^ (l15 & 7)) * 8;       // read col group (u16 offset)

    int kpos = 0;
    constexpr int nkt = K / 64;
    for (int t = 0; t < nkt; t++) {
#pragma unroll
        for (int q = 0; q < 4; q++) {
            glds16(pa + (size_t)q * 8 * rsA, lda + q * 8 * 64);
            glds16(pb + (size_t)q * 8 * rsB, ldb + q * 8 * 64);
        }
        if (AMAP == 2) {
            if (kpos == 8) { kpos = 0; pa += 64 - 8 * 256; pb += 64 - 8 * 256; }
            else           { kpos++;  pa += 256;           pb += 256; }
        } else { pa += 64; pb += 64; }
        __builtin_amdgcn_s_waitcnt(0);
        __syncthreads();
#pragma unroll
        for (int ks = 0; ks < 2; ks++) {
            bf16x8 af[4], bfr[4];
#pragma unroll
            for (int i = 0; i < 4; i++)
                af[i] = *(const bf16x8*)&As[(wm + i * 16 + l15) * 64 + (rg ^ (ks * 32))];
#pragma unroll
            for (int j = 0; j < 4; j++)
                bfr[j] = *(const bf16x8*)&Bs[(wn + j * 16 + l15) * 64 + (rg ^ (ks * 32))];
#pragma unroll
            for (int i = 0; i < 4; i++)
#pragma unroll
                for (int j = 0; j < 4; j++)
                    acc[i][j] = __builtin_amdgcn_mfma_f32_16x16x32_bf16(
                        af[i], bfr[j], acc[i][j], 0, 0, 0);
        }
        __syncthreads();
    }

    float bv[4];
#pragma unroll
    for (int j = 0; j < 4; j++) bv[j] = bf2f(bias[n0 + wn + j * 16 + l15]);
#pragma unroll
    for (int i = 0; i < 4; i++) {
#pragma unroll
        for (int j = 0; j < 4; j++) {
            int n = n0 + wn + j * 16 + l15;
            int mbase = m0 + wm + i * 16 + quad * 4;
            float o[4];
#pragma unroll
            for (int r = 0; r < 4; r++) {
                float v = acc[i][j][r] + bv[j];
                if (EPI == 1) v = fmaxf(v, 0.0f);
                o[r] = v;
            }
            if (EPI == 2) {
#pragma unroll
                for (int r = 0; r < 4; r++) {
                    int m = mbase + r;
                    float v = (o[r] + resid[(size_t)m * N + n]) * mask[m];
                    ((float*)Cp)[(size_t)m * N + n] = v;
                }
            } else if (EPI == 3) {
                if (n0 < 512) {
#pragma unroll
                    for (int r = 0; r < 4; r++)
                        ((u16*)Cp)[(size_t)(mbase + r) * 512 + n] = f2bf(o[r]);
                } else {
                    int dg = n - 512;                    // 0..255
                    int bb = mbase >> 10, tt = mbase & 1023;
                    ushort4 pk;
                    pk.x = f2bf(o[0]); pk.y = f2bf(o[1]);
                    pk.z = f2bf(o[2]); pk.w = f2bf(o[3]);
                    *(ushort4*)&vout[(size_t)((dg >> 7) + (bb << 1)) * (128 * 1024)
                                     + (size_t)(dg & 127) * 1024 + tt] = pk;
                }
            } else {
#pragma unroll
                for (int r = 0; r < 4; r++)
                    ((u16*)Cp)[(size_t)(mbase + r) * N + n] = f2bf(o[r]);
            }
        }
    }
}

// ----------------------- conv1 GEMM: 256x256 deep pipeline -----------------
// C[M,1024] = im2col(Hpad)[M,2304] @ W1R^T, bias+relu, bf16 out.
// A is address-linear: A[m][k] = Hpad[((m>>10)*TPAD + (m&1023))*256 + k].
// 8 waves (2Mx4N), per-wave 128x64 C. BK=64, 2-slot LDS dbuf (128 KiB),
// 4 half-tiles/k-tile staged 1/phase via glds16 (2 loads/thread/phase).
// 4 phases/k-tile: q0 {rd A.k0 + B.n01.k0 | stage B(t+1).h0 | 16 MFMA}
//                  q1 {rd A.k1 + B.n01.k1 | stage B(t+1).h1 | 16 MFMA}
//                  q2 {rd B.n23.k0        | stage A(t+2).h0 | 16 MFMA}
//                  q3 {rd B.n23.k1        | stage A(t+2).h1 | 16 MFMA}
// Counted vmcnt(4) once per k-tile (3 half-tiles stay in flight); raw
// s_barrier with lgkmcnt(0) drains; A(t+2) stages into slot s only after
// q1's barrier retires all reads of A(t) (A read only in q0/q1).
// [r1-verified: 142.5us, 47% MfmaUtil, 0 bank conflicts, VGPR 116]
// + XCD swizzle (sole delta vs r1): 512 blocks = 8 XCD x 64; each XCD pair
// shares one n-column (B-panel 1.18MB L2-resident) x 64 m-tiles.
__global__ __launch_bounds__(512, 2)
void gemm_conv1_8p(const u16* __restrict__ Ag, const u16* __restrict__ Wg,
                   const u16* __restrict__ bias, u16* __restrict__ Cp) {
    __shared__ __align__(16) u16 As[2][16384];
    __shared__ __align__(16) u16 Bs[2][16384];
    const int tid  = threadIdx.x;
    const int lane = tid & 63;
    const int wave = tid >> 6;
    const int quad = lane >> 4, l15 = lane & 15;
    const int wr = wave >> 2, wc = wave & 3;
    // XCD-aware bijective swizzle, gated to the full grid (4 x 128).
    int ntile, mtile;
    if (gridDim.y == 128) {
        const int f   = blockIdx.y * 4 + blockIdx.x;
        const int xcd = f & 7, pos = f >> 3;       // pos 0..63
        ntile = xcd >> 1;                          // n-column per XCD pair
        mtile = ((xcd & 1) << 6) + pos;            // 0..127
    } else { ntile = blockIdx.x; mtile = blockIdx.y; }
    const int m0 = mtile << 8, n0 = ntile << 8;
    const int hr0 = (m0 >> 10) * TPAD + (m0 & 1023);
    const int srow = tid >> 3, sch = tid & 7;

    // staging pointers, z = half*2 + issue (rows z*64 + srow), swizzled chunk
    const u16* pA[4];
    const u16* pB[4];
#pragma unroll
    for (int z = 0; z < 4; z++) {
        int r  = z * 64 + srow;
        int ch = (sch ^ (r & 7)) * 8;
        pA[z] = Ag + (size_t)(hr0 + r) * 256 + ch;
        pB[z] = Wg + (size_t)(n0 + r) * KCONV + ch;
    }
    const int ld0 = tid * 8;   // u16 offset: linear LDS dest (lane*16 B)

    // prologue: A(0) halves, B(0) halves, A(1) halves -> 12 loads/thread
#pragma unroll
    for (int z = 0; z < 4; z++) glds16(pA[z], &As[0][z * 4096 + ld0]);
#pragma unroll
    for (int z = 0; z < 4; z++) glds16(pB[z], &Bs[0][z * 4096 + ld0]);
#pragma unroll
    for (int z = 0; z < 4; z++) { pA[z] += 64; glds16(pA[z], &As[1][z * 4096 + ld0]); }

    const int cA0  = (quad ^ (l15 & 7)) * 8;   // k-half 0 read chunk
    const int cA1  = cA0 ^ 32;                 // k-half 1
    const int arow = (wr * 128 + l15) * 64;    // + mf*1024
    const int brow = (wc * 64  + l15) * 64;    // + nf*1024

    f32x4 acc[8][4] = {};

#pragma unroll 1
    for (int t = 0; t < NKT_C1; t++) {
        const int s = t & 1;
        u16* AsS = As[s];
        u16* BsS = Bs[s];
        u16* AsP = As[s];        // A(t+2) -> same slot (free after q1)
        u16* BsP = Bs[s ^ 1];    // B(t+1) -> other slot
        bf16x8 a0[8], a1[8], b0, b1;

        // ------------------------------ q0 -------------------------------
        if (t < NKT_C1 - 1) asm volatile("s_waitcnt vmcnt(4)" ::: "memory");
        else                asm volatile("s_waitcnt vmcnt(0)" ::: "memory");
        __builtin_amdgcn_s_barrier();
        asm volatile("" ::: "memory");
#pragma unroll
        for (int mf = 0; mf < 8; mf++)
            a0[mf] = *(const bf16x8*)&AsS[arow + mf * 1024 + cA0];
        b0 = *(const bf16x8*)&BsS[brow + cA0];
        b1 = *(const bf16x8*)&BsS[brow + 1024 + cA0];
        if (t + 1 < NKT_C1) {
            pB[0] += 64; pB[1] += 64;
            glds16(pB[0], &BsP[ld0]);
            glds16(pB[1], &BsP[4096 + ld0]);
        }
        __builtin_amdgcn_s_setprio(1);
#pragma unroll
        for (int mf = 0; mf < 8; mf++) {
            acc[mf][0] = __builtin_amdgcn_mfma_f32_16x16x32_bf16(a0[mf], b0, acc[mf][0], 0, 0, 0);
            acc[mf][1] = __builtin_amdgcn_mfma_f32_16x16x32_bf16(a0[mf], b1, acc[mf][1], 0, 0, 0);
        }
        __builtin_amdgcn_s_setprio(0);
        asm volatile("s_waitcnt lgkmcnt(0)" ::: "memory");
        __builtin_amdgcn_s_barrier();
        asm volatile("" ::: "memory");

        // ------------------------------ q1 -------------------------------
#pragma unroll
        for (int mf = 0; mf < 8; mf++)
            a1[mf] = *(const bf16x8*)&AsS[arow + mf * 1024 + cA1];
        b0 = *(const bf16x8*)&BsS[brow + cA1];
        b1 = *(const bf16x8*)&BsS[brow + 1024 + cA1];
        if (t + 1 < NKT_C1) {
            pB[2] += 64; pB[3] += 64;
            glds16(pB[2], &BsP[2 * 4096 + ld0]);
            glds16(pB[3], &BsP[3 * 4096 + ld0]);
        }
        __builtin_amdgcn_s_setprio(1);
#pragma unroll
        for (int mf = 0; mf < 8; mf++) {
            acc[mf][0] = __builtin_amdgcn_mfma_f32_16x16x32_bf16(a1[mf], b0, acc[mf][0], 0, 0, 0);
            acc[mf][1] = __builtin_amdgcn_mfma_f32_16x16x32_bf16(a1[mf], b1, acc[mf][1], 0, 0, 0);
        }
        __builtin_amdgcn_s_setprio(0);
        asm volatile("s_waitcnt lgkmcnt(0)" ::: "memory");
        __builtin_amdgcn_s_barrier();
        asm volatile("" ::: "memory");

        // ------------------------------ q2 -------------------------------
        b0 = *(const bf16x8*)&BsS[brow + 2 * 1024 + cA0];
        b1 = *(const bf16x8*)&BsS[brow + 3 * 1024 + cA0];
        if (t + 2 < NKT_C1) {
            pA[0] += 64; pA[1] += 64;
            glds16(pA[0], &AsP[ld0]);
            glds16(pA[1], &AsP[4096 + ld0]);
        }
        __builtin_amdgcn_s_setprio(1);
#pragma unroll
        for (int mf = 0; mf < 8; mf++) {
            acc[mf][2] = __builtin_amdgcn_mfma_f32_16x16x32_bf16(a0[mf], b0, acc[mf][2], 0, 0, 0);
            acc[mf][3] = __builtin_amdgcn_mfma_f32_16x16x32_bf16(a0[mf], b1, acc[mf][3], 0, 0, 0);
        }
        __builtin_amdgcn_s_setprio(0);
        asm volatile("s_waitcnt lgkmcnt(0)" ::: "memory");
        __builtin_amdgcn_s_barrier();
        asm volatile("" ::: "memory");

        // ------------------------------ q3 -------------------------------
        b0 = *(const bf16x8*)&BsS[brow + 2 * 1024 + cA1];
        b1 = *(const bf16x8*)&BsS[brow + 3 * 1024 + cA1];
        if (t + 2 < NKT_C1) {
            pA[2] += 64; pA[3] += 64;
            glds16(pA[2], &AsP[2 * 4096 + ld0]);
            glds16(pA[3], &AsP[3 * 4096 + ld0]);
        }
        __builtin_amdgcn_s_setprio(1);
#pragma unroll
        for (int mf = 0; mf < 8; mf++) {
            acc[mf][2] = __builtin_amdgcn_mfma_f32_16x16x32_bf16(a1[mf], b0, acc[mf][2], 0, 0, 0);
            acc[mf][3] = __builtin_amdgcn_mfma_f32_16x16x32_bf16(a1[mf], b1, acc[mf][3], 0, 0, 0);
        }
        __builtin_amdgcn_s_setprio(0);
        asm volatile("s_waitcnt lgkmcnt(0)" ::: "memory");
        // next iteration's q0 provides the vmcnt + barrier
    }

    // epilogue: bias + relu -> bf16 C [M][1024]
    float bv[4];
#pragma unroll
    for (int nf = 0; nf < 4; nf++)
        bv[nf] = bf2f(bias[n0 + wc * 64 + nf * 16 + l15]);
#pragma unroll
    for (int mf = 0; mf < 8; mf++) {
        const int mr = m0 + wr * 128 + mf * 16 + quad * 4;
#pragma unroll
        for (int nf = 0; nf < 4; nf++) {
            const int cc = n0 + wc * 64 + nf * 16 + l15;
#pragma unroll
            for (int r = 0; r < 4; r++) {
                float v = fmaxf(acc[mf][nf][r] + bv[nf], 0.0f);
                Cp[(size_t)(mr + r) * 1024 + cc] = f2bf(v);
            }
        }
    }
}

// --------------------------- flash MFMA attention --------------------------
// QKV [Mc][512] bf16 (q|k, head h at cols h*128 / 256+h*128).
// Vg [hb][128 d][1024 t] bf16 (pre-transposed V).
// Grid (hb fastest -> XCD locality, qt8 0..7), 256 thr, 128 q/block
// (2 sub-tiles of 16 q per wave). K-tiles of 64 keys, glds16 staging with
// XOR-chunk swizzle, B-frags shared across subs, online softmax, O -> Hpad.
// LDS 54KB: Ks 64x128, Vt 128x64, Ps 4x32x72, npS.
__global__ __launch_bounds__(256, 2)
void attn_mfma(const u16* __restrict__ QKV, const u16* __restrict__ Vg,
               const float* __restrict__ NPg, u16* __restrict__ Hp) {
    __shared__ __align__(16) u16 Ks[64 * 128];
    __shared__ __align__(16) u16 Vt[128 * 64];
    __shared__ __align__(16) u16 Ps[4 * 32 * 72];
    __shared__ float npS[1024];
    const int tid  = threadIdx.x;
    const int wave = tid >> 6, lane = tid & 63;
    const int quad = lane >> 4, l15 = lane & 15;
    const int hb = blockIdx.x;
    const int h = hb & (NH_ - 1), b = hb >> 1;
    const int t0 = blockIdx.y * 128;
    const float scale = 0.08838834764831845f;  // 1/sqrt(128)
    u16* Psw = Ps + wave * 32 * 72;
    const u16* Vgh = Vg + (size_t)hb * (128 * 1024);

    for (int i = tid; i < 1024; i += 256) npS[i] = NPg[b * 1024 + i];

    bf16x8 q_a[2][4];
#pragma unroll
    for (int sub = 0; sub < 2; sub++)
#pragma unroll
        for (int s = 0; s < 4; s++)
            q_a[sub][s] = *(const bf16x8*)(QKV
                + (size_t)(b * 1024 + t0 + sub * 64 + wave * 16 + l15) * 512
                + h * DK_ + s * 32 + quad * 8);

    float m_st[2][4], l_st[2][4];
    f32x4 oacc[2][8] = {};
#pragma unroll
    for (int sub = 0; sub < 2; sub++)
#pragma unroll
        for (int r = 0; r < 4; r++) { m_st[sub][r] = -1e30f; l_st[sub][r] = 0.0f; }

    for (int kk = 0; kk < 16; kk++) {
        const int k0 = kk * 64;
        if (kk) __syncthreads();   // prev tile's Ks/Vt reads complete
        // ---- stage K tile + V^T tile via glds16 (XOR-chunk swizzle) ----
#pragma unroll
        for (int i = 0; i < 4; i++) {
            int c = i * 256 + tid;
            int key = c >> 4, gk = (c & 15) ^ (key & 15);
            glds16(QKV + (size_t)(b * 1024 + k0 + key) * 512 + 256 + h * DK_ + gk * 8,
                   Ks + (size_t)(i * 256 + wave * 64) * 8);
            int d = c >> 3, gv = (c & 7) ^ (d & 7);
            glds16(Vgh + (size_t)d * 1024 + k0 + gv * 8,
                   Vt + (size_t)(i * 256 + wave * 64) * 8);
        }
        __builtin_amdgcn_s_waitcnt(0);
        __syncthreads();

        // ---- S = Q K^T, kb shared across both q-subs ----
        f32x4 s4[2][4] = {};
#pragma unroll
        for (int nt = 0; nt < 4; nt++) {
#pragma unroll
            for (int s = 0; s < 4; s++) {
                bf16x8 kb = *(const bf16x8*)&Ks[(nt * 16 + l15) * 128
                                                + ((s * 4 + quad) ^ l15) * 8];
                s4[0][nt] = __builtin_amdgcn_mfma_f32_16x16x32_bf16(
                    q_a[0][s], kb, s4[0][nt], 0, 0, 0);
                s4[1][nt] = __builtin_amdgcn_mfma_f32_16x16x32_bf16(
                    q_a[1][s], kb, s4[1][nt], 0, 0, 0);
            }
        }

        // ---- mask + online softmax + P->LDS (per sub; Ps is wave-private) --
#pragma unroll
        for (int sub = 0; sub < 2; sub++) {
#pragma unroll
            for (int nt = 0; nt < 4; nt++) {
                bool pad = (npS[k0 + nt * 16 + l15] == 0.0f);
#pragma unroll
                for (int r = 0; r < 4; r++)
                    s4[sub][nt][r] = pad ? -1e30f : s4[sub][nt][r] * scale;
            }
            float alpha[4];
#pragma unroll
            for (int r = 0; r < 4; r++) {
                float v = fmaxf(fmaxf(s4[sub][0][r], s4[sub][1][r]),
                                fmaxf(s4[sub][2][r], s4[sub][3][r]));
#pragma unroll
                for (int d = 1; d < 16; d <<= 1) v = fmaxf(v, __shfl_xor(v, d, 64));
                float mnew = fmaxf(m_st[sub][r], v);
                alpha[r] = __expf(m_st[sub][r] - mnew);
                m_st[sub][r] = mnew;
                l_st[sub][r] *= alpha[r];
            }
#pragma unroll
            for (int nt = 0; nt < 4; nt++)
#pragma unroll
                for (int r = 0; r < 4; r++)
                    s4[sub][nt][r] = __expf(s4[sub][nt][r] - m_st[sub][r]);
#pragma unroll
            for (int r = 0; r < 4; r++) {
                float v = s4[sub][0][r] + s4[sub][1][r] + s4[sub][2][r] + s4[sub][3][r];
#pragma unroll
                for (int d = 1; d < 16; d <<= 1) v += __shfl_xor(v, d, 64);
                l_st[sub][r] += v;
            }
#pragma unroll
            for (int dt = 0; dt < 8; dt++)
#pragma unroll
                for (int r = 0; r < 4; r++) oacc[sub][dt][r] *= alpha[r];
#pragma unroll
            for (int nt = 0; nt < 4; nt++)
#pragma unroll
                for (int r = 0; r < 4; r++)
                    Psw[(sub * 16 + quad * 4 + r) * 72 + nt * 16 + l15] =
                        f2bf(s4[sub][nt][r]);
        }

        // ---- O += P V, vb shared across both q-subs ----
#pragma unroll
        for (int ks = 0; ks < 2; ks++) {
            bf16x8 pa0 = *(const bf16x8*)&Psw[l15 * 72 + ks * 32 + quad * 8];
            bf16x8 pa1 = *(const bf16x8*)&Psw[(16 + l15) * 72 + ks * 32 + quad * 8];
#pragma unroll
            for (int dt = 0; dt < 8; dt++) {
                int d = dt * 16 + l15;
                bf16x8 vb = *(const bf16x8*)&Vt[d * 64
                                                + (((ks * 4 + quad) ^ (d & 7)) * 8)];
                oacc[0][dt] = __builtin_amdgcn_mfma_f32_16x16x32_bf16(
                    pa0, vb, oacc[0][dt], 0, 0, 0);
                oacc[1][dt] = __builtin_amdgcn_mfma_f32_16x16x32_bf16(
                    pa1, vb, oacc[1][dt], 0, 0, 0);
            }
        }
    }

    // ---- epilogue: O / l -> Hpad ----
#pragma unroll
    for (int sub = 0; sub < 2; sub++)
#pragma unroll
        for (int r = 0; r < 4; r++) {
            float inv = 1.0f / l_st[sub][r];
            int t = t0 + sub * 64 + wave * 16 + quad * 4 + r;
            size_t orow = (size_t)(b * TPAD + 4 + t) * D_ + h * DK_;
#pragma unroll
            for (int dt = 0; dt < 8; dt++)
                Hp[orow + dt * 16 + l15] = f2bf(oacc[sub][dt][r] * inv);
        }
}

// ------------------------------- driver ------------------------------------

static inline int cdiv(int a, int b) { return (a + b - 1) / b; }

extern "C" void kernel_launch(void* const* d_in, const int* in_sizes, int n_in,
                              void* d_out, int out_size, void* d_ws, size_t ws_size,
                              hipStream_t stream) {
    const int* seq = (const int*)d_in[0];
    const int* pos = (const int*)d_in[1];
    (void)in_sizes; (void)n_in;

    int   cb = 8, w1L = 1;
    int*   FLAG; float* X; float* NP; u16* Hpad; u16* SCR; u16* W1R;
    u16 *WEMB, *PEMB, *QKVW, *QKVB, *FCW, *FCB, *G1c, *B1c, *C1B, *C2W, *C2B, *G2c, *B2c;

    unsigned char* wsb = (unsigned char*)d_ws;
    size_t off;
    auto build = [&](int cb_, int w1L_) -> size_t {
        off = 0;
        auto take = [&](size_t bytes) {
            unsigned char* p = wsb + off;
            off += (bytes + 255) & ~(size_t)255;
            return p;
        };
        FLAG = (int*)  take(4);
        X    = (float*)take((size_t)MROWS * D_ * 4);
        NP   = (float*)take((size_t)MROWS * 4);
        Hpad = (u16*)  take((size_t)cb_ * TPAD * D_ * 2);
        SCR  = (u16*)  take((size_t)cb_ * T_ * DH_ * 2);
        W1R  = (u16*)  take((size_t)w1L_ * DH_ * KCONV * 2);
        WEMB = (u16*)  take((size_t)300 * D_ * 2);
        PEMB = (u16*)  take((size_t)3001 * D_ * 2);
        QKVW = (u16*)  take((size_t)L_ * 3 * D_ * D_ * 2);
        QKVB = (u16*)  take((size_t)L_ * 3 * D_ * 2);
        FCW  = (u16*)  take((size_t)L_ * D_ * D_ * 2);
        FCB  = (u16*)  take((size_t)L_ * D_ * 2);
        G1c  = (u16*)  take((size_t)L_ * D_ * 2);
        B1c  = (u16*)  take((size_t)L_ * D_ * 2);
        C1B  = (u16*)  take((size_t)L_ * DH_ * 2);
        C2W  = (u16*)  take((size_t)L_ * D_ * DH_ * 2);
        C2B  = (u16*)  take((size_t)L_ * D_ * 2);
        G2c  = (u16*)  take((size_t)L_ * D_ * 2);
        B2c  = (u16*)  take((size_t)L_ * D_ * 2);
        return off;
    };
    if      (build(32, L_) <= ws_size) { cb = 32; w1L = L_; }
    else if (build(8,  L_) <= ws_size) { cb = 8;  w1L = L_; }
    else if (build(8,  1)  <= ws_size) { cb = 8;  w1L = 1;  }
    else {
        sentinel_kernel<<<cdiv(out_size, 256), 256, 0, stream>>>(d_out, out_size);
        return;
    }
    const int nch = B_ / cb;
    const int Mc  = cb * T_;

    detect_kernel<<<1, 256, 0, stream>>>(d_in[2], FLAG);
    auto cvt = [&](const void* src, u16* dst, int n) {
        cvt_any_kernel<<<cdiv(n, 256), 256, 0, stream>>>(src, dst, n, FLAG);
    };
    cvt(d_in[2],  WEMB, 300 * D_);
    cvt(d_in[3],  PEMB, 3001 * D_);
    cvt(d_in[4],  QKVW, L_ * 3 * D_ * D_);
    cvt(d_in[5],  QKVB, L_ * 3 * D_);
    cvt(d_in[6],  FCW,  L_ * D_ * D_);
    cvt(d_in[7],  FCB,  L_ * D_);
    cvt(d_in[8],  G1c,  L_ * D_);
    cvt(d_in[9],  B1c,  L_ * D_);
    cvt(d_in[11], C1B,  L_ * DH_);
    cvt(d_in[12], C2W,  L_ * D_ * DH_);
    cvt(d_in[13], C2B,  L_ * D_);
    cvt(d_in[14], G2c,  L_ * D_);
    cvt(d_in[15], B2c,  L_ * D_);
    if (w1L == L_) {
        int n = L_ * DH_ * KCONV;
        w1_reorder2_kernel<<<cdiv(n, 256), 256, 0, stream>>>(
            (const float*)d_in[10], (const u16*)d_in[10], W1R, n, FLAG);
    }

    embed_kernel<<<MROWS, 256, 0, stream>>>(seq, pos, WEMB, PEMB, X, NP);
    zero_pad_kernel<<<cb * 8, 256, 0, stream>>>(Hpad, cb);

    for (int l = 0; l < L_; l++) {
        for (int c = 0; c < nch; c++) {
            const size_t ro = (size_t)c * Mc;
            u16* QKV = SCR;                              // [Mc][512] q|k
            u16* Vg  = SCR + (size_t)Mc * 512;           // [NH*cb][128][1024]
            ln_kernel<<<Mc / 4, 256, 0, stream>>>(
                X + ro * D_, G1c + l * D_, B1c + l * D_, Hpad);
            gemm_mfma<1, 3, 256><<<dim3(6, Mc / 128), 256, 0, stream>>>(
                Hpad, QKVW + (size_t)l * 3 * D_ * D_, QKVB + l * 3 * D_,
                nullptr, nullptr, QKV, Vg, Mc, 768);
            attn_mfma<<<dim3(NH_ * cb, 8), 256, 0, stream>>>(
                QKV, Vg, NP + ro, Hpad);
            gemm_mfma<1, 2, 256><<<dim3(2, Mc / 128), 256, 0, stream>>>(
                Hpad, FCW + (size_t)l * D_ * D_, FCB + l * D_,
                X + ro * D_, NP + ro, X + ro * D_, nullptr, Mc, D_);
        }
        const u16* w1p = W1R + (w1L == L_ ? (size_t)l * DH_ * KCONV : 0);
        if (w1L != L_) {
            int n = DH_ * KCONV;
            w1_reorder2_kernel<<<cdiv(n, 256), 256, 0, stream>>>(
                (const float*)d_in[10] + (size_t)l * DH_ * D_ * 9,
                (const u16*)d_in[10] + (size_t)l * DH_ * D_ * 9,
                W1R, n, FLAG);
        }
        for (int c = 0; c < nch; c++) {
            const size_t ro = (size_t)c * Mc;
            ln_kernel<<<Mc / 4, 256, 0, stream>>>(
                X + ro * D_, G2c + l * D_, B2c + l * D_, Hpad);
            gemm_conv1_8p<<<dim3(4, Mc / 256), 512, 0, stream>>>(
                Hpad, w1p, C1B + l * DH_, SCR);
            gemm_mfma<0, 2, 1024><<<dim3(2, Mc / 128), 256, 0, stream>>>(
                SCR, C2W + (size_t)l * D_ * DH_, C2B + l * D_,
                X + ro * D_, NP + ro, X + ro * D_, nullptr, Mc, D_);
        }
    }

    out_kernel<<<cdiv(out_size, 256), 256, 0, stream>>>(X, NP, d_out, out_size, FLAG);
}